// Round 3
// baseline (74.931 us; speedup 1.0000x reference)
//
#include <hip/hip_runtime.h>
#include <stdint.h>

#define NUM_BBOX    2
#define NUM_CLASSES 20
#define NUM_GRID    7
#define BATCH       64
#define NCELL  (BATCH * NUM_GRID * NUM_GRID)   // 3136
#define NCAND  (NCELL * NUM_BBOX)              // 6272
#define NGROUP (BATCH * NUM_CLASSES)           // 1280
#define MAXG   98
#define NJT    8
#define JTILE  (NCAND / NJT)                   // 784

// ---- workspace layout (bytes) ----
#define WS_SCORE     0         // f32[6272]            25088
#define WS_CELLBOX   25088     // f32[3136*4]          50176
#define WS_CELLLAB   75264     // f32[3136]            12544
#define WS_KEYS      87808     // u64[6272]            50176
#define WS_KEEP      137984    // f32[6272]            25088
#define WS_RANK      163072    // u32[6272]            25088

// monotone float -> sortable u32 (ascending float == ascending u32)
__device__ __forceinline__ unsigned fkey(float f) {
    unsigned u = __float_as_uint(f);
    return (u & 0x80000000u) ? ~u : (u | 0x80000000u);
}

__global__ void k_decode(const float* __restrict__ in,
                         float* __restrict__ score,
                         float* __restrict__ cellBox,
                         float* __restrict__ cellLabel,
                         unsigned long long* __restrict__ keys,
                         float* __restrict__ keepOrig,
                         unsigned* __restrict__ rank) {
    int cell = blockIdx.x * blockDim.x + threadIdx.x;
    if (cell >= NCELL) return;
    const float* p = in + cell * (NUM_BBOX * (5 + NUM_CLASSES));
    int rc = cell % (NUM_GRID * NUM_GRID);
    int r = rc / NUM_GRID, c = rc % NUM_GRID;

    // per-bbox score = max_cls (prob*conf)  -- mul then max, matching reference
    float sc[NUM_BBOX];
    for (int bb = 0; bb < NUM_BBOX; ++bb) {
        const float* q = p + bb * 25;
        float conf = q[4];
        float m = __fmul_rn(q[5], conf);
        for (int k = 1; k < NUM_CLASSES; ++k)
            m = fmaxf(m, __fmul_rn(q[5 + k], conf));
        sc[bb] = m;
    }
    int best = (sc[1] > sc[0]) ? 1 : 0;   // first-occurrence argmax over 2
    const float* q = p + best * 25;

    // label = argmax over classes (first occurrence) + 1
    int lab = 0; float bv = q[5];
    for (int k = 1; k < NUM_CLASSES; ++k)
        if (q[5 + k] > bv) { bv = q[5 + k]; lab = k; }

    // box: x uses row index, y uses col index (as in reference)
    float x  = __fdiv_rn(__fadd_rn(q[0], (float)r), 7.0f);
    float y  = __fdiv_rn(__fadd_rn(q[1], (float)c), 7.0f);
    float hw = __fmul_rn(q[2], 0.5f);
    float hh = __fmul_rn(q[3], 0.5f);
    float x1 = __fsub_rn(x, hw), y1 = __fsub_rn(y, hh);
    float x2 = __fadd_rn(x, hw), y2 = __fadd_rn(y, hh);

    cellBox[cell * 4 + 0] = x1;
    cellBox[cell * 4 + 1] = y1;
    cellBox[cell * 4 + 2] = x2;
    cellBox[cell * 4 + 3] = y2;
    cellLabel[cell] = (float)(lab + 1);

    for (int bb = 0; bb < NUM_BBOX; ++bb) {
        int idx = cell * NUM_BBOX + bb;
        score[idx] = sc[bb];
        keepOrig[idx] = 0.0f;
        rank[idx] = 0u;
        bool valid = sc[bb] > 0.5f;
        float kf = valid ? -sc[bb] : __builtin_inff();
        keys[idx] = ((unsigned long long)fkey(kf) << 32) | (unsigned)idx;
    }
}

// one thread per (batch,label) group; membership by direct scan of the
// batch's 98 candidates (valid <=> key top32 < 0x80000000, i.e. -score < 0).
// Greedy NMS in global-sorted order (key ascending).
__global__ void k_nms(const unsigned long long* __restrict__ keys,
                      const float* __restrict__ cellLabel,
                      const float* __restrict__ cellBox,
                      float* __restrict__ keepOrig) {
    int g = blockIdx.x * blockDim.x + threadIdx.x;
    if (g >= NGROUP) return;
    int b = g / NUM_CLASSES;
    float lab = (float)(g % NUM_CLASSES + 1);
    int base = b * MAXG;

    unsigned long long k[MAXG]; int n = 0;
    for (int t = 0; t < MAXG; ++t) {
        int idx = base + t;
        unsigned long long key = keys[idx];
        if ((unsigned)(key >> 32) < 0x80000000u && cellLabel[idx >> 1] == lab)
            k[n++] = key;
    }
    if (n == 0) return;

    // insertion sort ascending (== global sorted order restricted to group)
    for (int i = 1; i < n; ++i) {
        unsigned long long v = k[i]; int j = i - 1;
        while (j >= 0 && k[j] > v) { k[j + 1] = k[j]; --j; }
        k[j + 1] = v;
    }

    float4 kept[MAXG]; int nk = 0;
    for (int i = 0; i < n; ++i) {
        int idx  = (int)(unsigned)k[i];
        int cell = idx >> 1;
        float4 bx = *(const float4*)(cellBox + cell * 4);
        bool sup = false;
        for (int t = 0; t < nk && !sup; ++t) {
            float4 a = kept[t];
            float xx1 = fmaxf(a.x, bx.x), yy1 = fmaxf(a.y, bx.y);
            float xx2 = fminf(a.z, bx.z), yy2 = fminf(a.w, bx.w);
            float w = fmaxf(__fsub_rn(xx2, xx1), 0.0f);
            float h = fmaxf(__fsub_rn(yy2, yy1), 0.0f);
            float inter = __fmul_rn(w, h);
            float aa = __fmul_rn(__fsub_rn(a.z, a.x), __fsub_rn(a.w, a.y));
            float ab = __fmul_rn(__fsub_rn(bx.z, bx.x), __fsub_rn(bx.w, bx.y));
            float denom = __fadd_rn(__fsub_rn(__fadd_rn(aa, ab), inter), 1e-9f);
            float iou = __fdiv_rn(inter, denom);
            if (iou > 0.3f) sup = true;
        }
        if (!sup) { kept[nk++] = bx; keepOrig[idx] = 1.0f; }
    }
}

// rank[i] = #{ j : keys[j] < keys[i] }  (keys unique -> bijective rank).
// grid (98 i-blocks, 8 j-tiles) x 64 threads; keys[j] is wave-uniform.
__global__ void __launch_bounds__(64) k_rank(
        const unsigned long long* __restrict__ keys,
        unsigned* __restrict__ rank) {
    int i  = blockIdx.x * 64 + (int)threadIdx.x;
    int j0 = blockIdx.y * JTILE;
    unsigned long long my = keys[i];
    unsigned r = 0;
    #pragma unroll 8
    for (int j = j0; j < j0 + JTILE; ++j)
        r += (keys[j] < my) ? 1u : 0u;
    atomicAdd(&rank[i], r);
}

// write source element i to its sorted position rank[i]
__global__ void __launch_bounds__(64) k_scatter(
        const unsigned* __restrict__ rank,
        const float* __restrict__ score,
        const float* __restrict__ cellBox,
        const float* __restrict__ cellLabel,
        const float* __restrict__ keepOrig,
        float* __restrict__ out) {
    int i = blockIdx.x * 64 + (int)threadIdx.x;
    unsigned r = rank[i];
    int cell = i >> 1;
    // idx = b*98 + (rc*2+bb) with rc*2+bb < 98  ->  i/98 == batch id
    out[r] = (float)(i / 98);
    float4 bx = *(const float4*)(cellBox + cell * 4);
    *(float4*)(out + NCAND + r * 4) = bx;
    out[NCAND * 5 + r] = cellLabel[cell];
    out[NCAND * 6 + r] = score[i];
    out[NCAND * 7 + r] = keepOrig[i];
}

extern "C" void kernel_launch(void* const* d_in, const int* in_sizes, int n_in,
                              void* d_out, int out_size, void* d_ws, size_t ws_size,
                              hipStream_t stream) {
    const float* in = (const float*)d_in[0];
    char* ws = (char*)d_ws;
    float*              score     = (float*)(ws + WS_SCORE);
    float*              cellBox   = (float*)(ws + WS_CELLBOX);
    float*              cellLabel = (float*)(ws + WS_CELLLAB);
    unsigned long long* keys      = (unsigned long long*)(ws + WS_KEYS);
    float*              keepOrig  = (float*)(ws + WS_KEEP);
    unsigned*           rank      = (unsigned*)(ws + WS_RANK);
    float* out = (float*)d_out;

    k_decode<<<(NCELL + 63) / 64, 64, 0, stream>>>(in, score, cellBox, cellLabel,
                                                   keys, keepOrig, rank);
    k_nms<<<(NGROUP + 63) / 64, 64, 0, stream>>>(keys, cellLabel, cellBox, keepOrig);
    k_rank<<<dim3(NCAND / 64, NJT), 64, 0, stream>>>(keys, rank);
    k_scatter<<<NCAND / 64, 64, 0, stream>>>(rank, score, cellBox, cellLabel, keepOrig, out);
}

// Round 4
// 32.345 us; speedup vs baseline: 2.3166x; 2.3166x over previous
//
#include <hip/hip_runtime.h>
#include <stdint.h>

#define NUM_BBOX    2
#define NUM_CLASSES 20
#define NUM_GRID    7
#define BATCH       64
#define NCELL  (BATCH * NUM_GRID * NUM_GRID)   // 3136
#define NCAND  (NCELL * NUM_BBOX)              // 6272
#define NGROUP (BATCH * NUM_CLASSES)           // 1280
#define MAXG   98
#define NJT    8
#define JTILE  (NCAND / NJT)                   // 784

// ---- workspace layout (bytes) ----
#define WS_SCORE     0         // f32[6272]            25088
#define WS_CELLBOX   25088     // f32[3136*4]          50176
#define WS_CELLLAB   75264     // f32[3136]            12544
#define WS_KEYS      87808     // u64[6272]            50176
#define WS_KEEP      137984    // f32[6272]            25088
#define WS_RANK      163072    // u32[6272]            25088

// monotone float -> sortable u32 (ascending float == ascending u32)
__device__ __forceinline__ unsigned fkey(float f) {
    unsigned u = __float_as_uint(f);
    return (u & 0x80000000u) ? ~u : (u | 0x80000000u);
}

__global__ void k_decode(const float* __restrict__ in,
                         float* __restrict__ score,
                         float* __restrict__ cellBox,
                         float* __restrict__ cellLabel,
                         unsigned long long* __restrict__ keys,
                         float* __restrict__ keepOrig,
                         unsigned* __restrict__ rank) {
    int cell = blockIdx.x * blockDim.x + threadIdx.x;
    if (cell >= NCELL) return;
    const float* p = in + cell * (NUM_BBOX * (5 + NUM_CLASSES));
    int rc = cell % (NUM_GRID * NUM_GRID);
    int r = rc / NUM_GRID, c = rc % NUM_GRID;

    // per-bbox score = max_cls (prob*conf)  -- mul then max, matching reference
    float sc[NUM_BBOX];
    for (int bb = 0; bb < NUM_BBOX; ++bb) {
        const float* q = p + bb * 25;
        float conf = q[4];
        float m = __fmul_rn(q[5], conf);
        for (int k = 1; k < NUM_CLASSES; ++k)
            m = fmaxf(m, __fmul_rn(q[5 + k], conf));
        sc[bb] = m;
    }
    int best = (sc[1] > sc[0]) ? 1 : 0;   // first-occurrence argmax over 2
    const float* q = p + best * 25;

    // label = argmax over classes (first occurrence) + 1
    int lab = 0; float bv = q[5];
    for (int k = 1; k < NUM_CLASSES; ++k)
        if (q[5 + k] > bv) { bv = q[5 + k]; lab = k; }

    // box: x uses row index, y uses col index (as in reference)
    float x  = __fdiv_rn(__fadd_rn(q[0], (float)r), 7.0f);
    float y  = __fdiv_rn(__fadd_rn(q[1], (float)c), 7.0f);
    float hw = __fmul_rn(q[2], 0.5f);
    float hh = __fmul_rn(q[3], 0.5f);
    float x1 = __fsub_rn(x, hw), y1 = __fsub_rn(y, hh);
    float x2 = __fadd_rn(x, hw), y2 = __fadd_rn(y, hh);

    cellBox[cell * 4 + 0] = x1;
    cellBox[cell * 4 + 1] = y1;
    cellBox[cell * 4 + 2] = x2;
    cellBox[cell * 4 + 3] = y2;
    cellLabel[cell] = (float)(lab + 1);

    for (int bb = 0; bb < NUM_BBOX; ++bb) {
        int idx = cell * NUM_BBOX + bb;
        score[idx] = sc[bb];
        keepOrig[idx] = 0.0f;
        rank[idx] = 0u;
        bool valid = sc[bb] > 0.5f;
        float kf = valid ? -sc[bb] : __builtin_inff();
        keys[idx] = ((unsigned long long)fkey(kf) << 32) | (unsigned)idx;
    }
}

__device__ __forceinline__ float iou_rn(float4 a, float4 b) {
    float xx1 = fmaxf(a.x, b.x), yy1 = fmaxf(a.y, b.y);
    float xx2 = fminf(a.z, b.z), yy2 = fminf(a.w, b.w);
    float w = fmaxf(__fsub_rn(xx2, xx1), 0.0f);
    float h = fmaxf(__fsub_rn(yy2, yy1), 0.0f);
    float inter = __fmul_rn(w, h);
    float aa = __fmul_rn(__fsub_rn(a.z, a.x), __fsub_rn(a.w, a.y));
    float ab = __fmul_rn(__fsub_rn(b.z, b.x), __fsub_rn(b.w, b.y));
    float denom = __fadd_rn(__fsub_rn(__fadd_rn(aa, ab), inter), 1e-9f);
    return __fdiv_rn(inter, denom);
}

// one 64-lane workgroup per (batch,label) group. Membership via ballot,
// order via rank-by-count (keys unique, == global sorted order restricted
// to the group), greedy suppression with wave-parallel IoU.
__global__ void __launch_bounds__(64) k_nms(
        const unsigned long long* __restrict__ keys,
        const float* __restrict__ cellLabel,
        const float* __restrict__ cellBox,
        float* __restrict__ keepOrig) {
    __shared__ unsigned long long mkey[MAXG];
    __shared__ unsigned long long skey[MAXG];
    int g = blockIdx.x;
    int lane = (int)threadIdx.x;
    int b = g / NUM_CLASSES;
    float lab = (float)(g % NUM_CLASSES + 1);
    int base = b * MAXG;

    // slot 0: candidate t = lane (< 98 always); slot 1: t = lane+64 (lane<34)
    unsigned long long key0 = keys[base + lane];
    bool v0 = ((unsigned)(key0 >> 32) < 0x80000000u) &&
              (cellLabel[(base + lane) >> 1] == lab);
    unsigned long long key1 = 0; bool v1 = false;
    if (lane + 64 < MAXG) {
        key1 = keys[base + lane + 64];
        v1 = ((unsigned)(key1 >> 32) < 0x80000000u) &&
             (cellLabel[(base + lane + 64) >> 1] == lab);
    }

    unsigned long long b0 = __ballot(v0);
    unsigned long long b1 = __ballot(v1);
    int n0 = __popcll(b0);
    int n  = n0 + __popcll(b1);
    if (n == 0) return;

    unsigned long long below = (1ull << lane) - 1ull;
    if (v0) mkey[__popcll(b0 & below)] = key0;
    if (v1) mkey[n0 + __popcll(b1 & below)] = key1;
    __syncthreads();

    // sorted position = # members with smaller key
    for (int s = 0; s < 2; ++s) {
        int j = lane + s * 64;
        if (j < n) {
            unsigned long long kj = mkey[j];
            int r = 0;
            for (int i = 0; i < n; ++i) r += (mkey[i] < kj) ? 1 : 0;
            skey[r] = kj;
        }
    }
    __syncthreads();

    // member j (sorted) lives on lane j&63, slot j>>6
    float4 box0 = make_float4(0.f, 0.f, 0.f, 0.f), box1 = box0;
    int idx0 = 0, idx1 = 0, keep0 = 0, keep1 = 0;
    if (lane < n) {
        idx0 = (int)(unsigned)skey[lane];
        box0 = *(const float4*)(cellBox + (idx0 >> 1) * 4);
        keep0 = 1;
    }
    if (lane + 64 < n) {
        idx1 = (int)(unsigned)skey[lane + 64];
        box1 = *(const float4*)(cellBox + (idx1 >> 1) * 4);
        keep1 = 1;
    }

    for (int i = 0; i < n; ++i) {
        int srcl = i & 63;
        int ki = __shfl((i < 64) ? keep0 : keep1, srcl);
        if (ki) {
            float4 src = (i < 64) ? box0 : box1;
            float4 bi;
            bi.x = __shfl(src.x, srcl);
            bi.y = __shfl(src.y, srcl);
            bi.z = __shfl(src.z, srcl);
            bi.w = __shfl(src.w, srcl);
            if (keep0 && lane > i) {
                if (iou_rn(bi, box0) > 0.3f) keep0 = 0;
            }
            if (keep1 && lane + 64 > i) {
                if (iou_rn(bi, box1) > 0.3f) keep1 = 0;
            }
        }
    }
    if (keep0) keepOrig[idx0] = 1.0f;
    if (keep1) keepOrig[idx1] = 1.0f;
}

// rank[i] = #{ j : keys[j] < keys[i] }  (keys unique -> bijective rank).
// grid (98 i-blocks, 8 j-tiles) x 64 threads; keys[j] is wave-uniform.
__global__ void __launch_bounds__(64) k_rank(
        const unsigned long long* __restrict__ keys,
        unsigned* __restrict__ rank) {
    int i  = blockIdx.x * 64 + (int)threadIdx.x;
    int j0 = blockIdx.y * JTILE;
    unsigned long long my = keys[i];
    unsigned r = 0;
    #pragma unroll 8
    for (int j = j0; j < j0 + JTILE; ++j)
        r += (keys[j] < my) ? 1u : 0u;
    atomicAdd(&rank[i], r);
}

// write source element i to its sorted position rank[i]
__global__ void __launch_bounds__(64) k_scatter(
        const unsigned* __restrict__ rank,
        const float* __restrict__ score,
        const float* __restrict__ cellBox,
        const float* __restrict__ cellLabel,
        const float* __restrict__ keepOrig,
        float* __restrict__ out) {
    int i = blockIdx.x * 64 + (int)threadIdx.x;
    unsigned r = rank[i];
    int cell = i >> 1;
    // idx = b*98 + (rc*2+bb) with rc*2+bb < 98  ->  i/98 == batch id
    out[r] = (float)(i / 98);
    float4 bx = *(const float4*)(cellBox + cell * 4);
    *(float4*)(out + NCAND + r * 4) = bx;
    out[NCAND * 5 + r] = cellLabel[cell];
    out[NCAND * 6 + r] = score[i];
    out[NCAND * 7 + r] = keepOrig[i];
}

extern "C" void kernel_launch(void* const* d_in, const int* in_sizes, int n_in,
                              void* d_out, int out_size, void* d_ws, size_t ws_size,
                              hipStream_t stream) {
    const float* in = (const float*)d_in[0];
    char* ws = (char*)d_ws;
    float*              score     = (float*)(ws + WS_SCORE);
    float*              cellBox   = (float*)(ws + WS_CELLBOX);
    float*              cellLabel = (float*)(ws + WS_CELLLAB);
    unsigned long long* keys      = (unsigned long long*)(ws + WS_KEYS);
    float*              keepOrig  = (float*)(ws + WS_KEEP);
    unsigned*           rank      = (unsigned*)(ws + WS_RANK);
    float* out = (float*)d_out;

    k_decode<<<(NCELL + 63) / 64, 64, 0, stream>>>(in, score, cellBox, cellLabel,
                                                   keys, keepOrig, rank);
    k_nms<<<NGROUP, 64, 0, stream>>>(keys, cellLabel, cellBox, keepOrig);
    k_rank<<<dim3(NCAND / 64, NJT), 64, 0, stream>>>(keys, rank);
    k_scatter<<<NCAND / 64, 64, 0, stream>>>(rank, score, cellBox, cellLabel, keepOrig, out);
}